// Round 8
// baseline (111.984 us; speedup 1.0000x reference)
//
#include <hip/hip_runtime.h>

// channel_attention: the attention branch is the identity (softmax over m
// sums to 1 in einsum 'bdct,bdcm->bdct'). Output = LN_c(pW @ x + pb) per
// (b,d,t) column.
//
// R7 = R6 with the store-phase bug fixed. TILE_T=256: every VMEM
// instruction moves one full contiguous 1KB row (64 lanes x 16B). LDS held
// at 32KB (4 blocks/CU) by staging bf16: x converted during stage (feeds
// bf16 MFMA anyway), LN output y written back bf16 into the SAME buffer
// (column-disjoint -> safe), expanded to f32 on the store path.
// R6's bug: store kept a spurious half-loop -> lanes 32-63 read past the
// row (and LDS) end and stored into the next tile's t-range. Store is now
// a single pass: lane -> columns lane*4..lane*4+3, exact mirror of stage.

#define CC      64
#define TT      3000
#define TILE_T  256
#define NTB     12            // ceil(TT / TILE_T)
#define NWG     (256 * NTB)   // 3072 blocks, % 8 == 0 -> bijective swizzle
#define CPX     (NWG / 8)     // 384

typedef __attribute__((ext_vector_type(8)))  short short8;
typedef __attribute__((ext_vector_type(16))) float f32x16;

static __device__ __forceinline__ unsigned f2bf(float f) {
    // round-to-nearest-even f32 -> bf16 (inputs finite)
    unsigned u = __builtin_bit_cast(unsigned, f);
    return (u + 0x7FFFu + ((u >> 16) & 1u)) >> 16;
}

// ws layout: Wf = 4096 shorts (8 KB); Pf = 192 floats at +8192 B.
// Wf[((ct*4+kc)*64 + lane)*8 + e] = bf16(pW[co*CC + c]),
//   co = ct*32 + (lane&31), c = kc*16 + (lane>>5)*8 + e.
// Pf[a*64 + (ct*2+half)*16 + r] = {pb,pg,pbeta}[ct*32 + half*4 + (r&3) + 8*(r>>2)]
__global__ void pack_params(const float* __restrict__ pW,
                            const float* __restrict__ pb,
                            const float* __restrict__ pg,
                            const float* __restrict__ pbeta,
                            short* __restrict__ Wf, float* __restrict__ Pf)
{
    int i = blockIdx.x * 256 + threadIdx.x;
    if (i < 4096) {
        int e = i & 7, l = (i >> 3) & 63, f = i >> 9;
        int ct = f >> 2, kc = f & 3;
        int co = ct * 32 + (l & 31);
        int c  = kc * 16 + (l >> 5) * 8 + e;
        Wf[i] = (short)f2bf(pW[co * CC + c]);
    } else if (i < 4096 + 192) {
        int j = i - 4096;
        int a = j >> 6, q = j & 63;
        int r = q & 15, half = (q >> 4) & 1, ct = q >> 5;
        int co = ct * 32 + half * 4 + (r & 3) + 8 * (r >> 2);
        const float* src = (a == 0) ? pb : (a == 1) ? pg : pbeta;
        Pf[j] = src[co];
    }
}

__global__ __launch_bounds__(256, 4) void fused_mfma_ln(
    const float* __restrict__ x,    // [BD, CC, TT]
    const short* __restrict__ Wf,
    const float* __restrict__ Pf,
    float* __restrict__ out)        // [BD, CC, TT]
{
    __shared__ unsigned xs[CC * TILE_T / 2];   // 32 KB: [c][t] bf16 pairs

    const int bid = blockIdx.x;
    const int swz = (bid & 7) * CPX + (bid >> 3);   // XCD-chunked, bijective
    const int bd  = swz / NTB;
    const int tb  = swz - bd * NTB;
    const int t0  = tb * TILE_T;

    const int tid  = threadIdx.x;
    const int lane = tid & 63;
    const int wid  = tid >> 6;
    const int col  = lane & 31;
    const int half = lane >> 5;

    const size_t xbase = (size_t)bd * (CC * TT);

    // ---- Phase 1: stage x -> bf16 LDS. Round r: wave covers row c=r*4+wid
    // fully (64 lanes x float4 = 1KB contiguous), converts, ds_write_b64
    // (lanes stride 8B -> conflict-free).
    {
        int tq = t0 + lane * 4;
        if (tq > TT - 4) tq = TT - 4;       // tail clamp (dup, never stored)
        float4 tmp[16];
#pragma unroll
        for (int r = 0; r < 16; ++r)
            tmp[r] = *(const float4*)(x + xbase + (size_t)(r * 4 + wid) * TT + tq);
#pragma unroll
        for (int r = 0; r < 16; ++r) {
            const int c = r * 4 + wid;
            uint2 p;
            p.x = f2bf(tmp[r].x) | (f2bf(tmp[r].y) << 16);
            p.y = f2bf(tmp[r].z) | (f2bf(tmp[r].w) << 16);
            *(uint2*)&xs[c * (TILE_T / 2) + lane * 2] = p;
        }
    }
    __syncthreads();

    // W fragments (L2-hot after first blocks).
    short8 aW[2][4];
#pragma unroll
    for (int ct = 0; ct < 2; ++ct)
#pragma unroll
        for (int kc = 0; kc < 4; ++kc)
            aW[ct][kc] = ((const short8*)Wf)[(ct * 4 + kc) * 64 + lane];

    const unsigned short* xsh = (const unsigned short*)xs;
    unsigned short*       ysh = (unsigned short*)xs;

    // ---- Phase 2-4: two 128-col halves sequentially (keeps acc at 32 VGPR).
    // x-reads and y-writes are column-disjoint across waves AND halves in
    // byte space (identical [c][t]-bf16 indexing) -> no inner barriers.
#pragma unroll
    for (int h = 0; h < 2; ++h) {
        const int tcol = h * 128 + wid * 32 + col;

        short8 bx[4];
#pragma unroll
        for (int kc = 0; kc < 4; ++kc) {
            union { unsigned u[4]; short8 s; } cvt;
#pragma unroll
            for (int e = 0; e < 4; ++e) {
                const int c0 = kc * 16 + half * 8 + 2 * e;   // same rule as aW
                cvt.u[e] = (unsigned)xsh[c0 * TILE_T + tcol]
                         | ((unsigned)xsh[(c0 + 1) * TILE_T + tcol] << 16);
            }
            bx[kc] = cvt.s;
        }

        f32x16 acc[2];
#pragma unroll
        for (int r = 0; r < 16; ++r) { acc[0][r] = 0.0f; acc[1][r] = 0.0f; }
#pragma unroll
        for (int kc = 0; kc < 4; ++kc) {
            acc[0] = __builtin_amdgcn_mfma_f32_32x32x16_bf16(aW[0][kc], bx[kc], acc[0], 0, 0, 0);
            acc[1] = __builtin_amdgcn_mfma_f32_32x32x16_bf16(aW[1][kc], bx[kc], acc[1], 0, 0, 0);
        }

        // bias + LN stats (C/D: col=lane&31, row=ct*32+half*4+(r&3)+8*(r>>2))
        float s = 0.0f, s2 = 0.0f;
#pragma unroll
        for (int ct = 0; ct < 2; ++ct) {
            const float4* pbv = (const float4*)(Pf + (ct * 2 + half) * 16);
#pragma unroll
            for (int q = 0; q < 4; ++q) {
                const float4 b4 = pbv[q];
                acc[ct][q * 4 + 0] += b4.x;
                acc[ct][q * 4 + 1] += b4.y;
                acc[ct][q * 4 + 2] += b4.z;
                acc[ct][q * 4 + 3] += b4.w;
            }
#pragma unroll
            for (int r = 0; r < 16; ++r) {
                const float v = acc[ct][r];
                s += v;
                s2 = fmaf(v, v, s2);
            }
        }
        s  += __shfl_xor(s, 32);
        s2 += __shfl_xor(s2, 32);
        const float mu   = s * (1.0f / CC);
        const float rstd = rsqrtf(s2 * (1.0f / CC) - mu * mu + 1e-5f);

        // y writeback (bf16) into the same buffer, own column only.
#pragma unroll
        for (int ct = 0; ct < 2; ++ct) {
            const float4* pgv = (const float4*)(Pf + 64  + (ct * 2 + half) * 16);
            const float4* pev = (const float4*)(Pf + 128 + (ct * 2 + half) * 16);
#pragma unroll
            for (int q = 0; q < 4; ++q) {
                const float4 g4 = pgv[q];
                const float4 e4 = pev[q];
                const float gg[4] = {g4.x, g4.y, g4.z, g4.w};
                const float ee[4] = {e4.x, e4.y, e4.z, e4.w};
#pragma unroll
                for (int j = 0; j < 4; ++j) {
                    const int r  = q * 4 + j;
                    const int co = ct * 32 + half * 4 + (r & 3) + 8 * (r >> 2);
                    const float val = (acc[ct][r] - mu) * rstd * gg[j] + ee[j];
                    ysh[co * TILE_T + tcol] = (unsigned short)f2bf(val);
                }
            }
        }
    }
    __syncthreads();

    // ---- Phase 5: store, exact mirror of phase 1. One pass per row:
    // lane -> columns lane*4..lane*4+3 (uint2 = 4 bf16), expand to f32,
    // float4 store; 64 lanes x 16B = 1KB contiguous per row.
#pragma unroll
    for (int r = 0; r < 16; ++r) {
        const int c = r * 4 + wid;
        const int t = t0 + lane * 4;
        const uint2 v = *(const uint2*)&xs[c * (TILE_T / 2) + lane * 2];
        if (t < TT) {
            float4 o;
            o.x = __builtin_bit_cast(float, v.x << 16);
            o.y = __builtin_bit_cast(float, v.x & 0xFFFF0000u);
            o.z = __builtin_bit_cast(float, v.y << 16);
            o.w = __builtin_bit_cast(float, v.y & 0xFFFF0000u);
            *(float4*)(out + xbase + (size_t)c * TT + t) = o;
        }
    }
}

extern "C" void kernel_launch(void* const* d_in, const int* in_sizes, int n_in,
                              void* d_out, int out_size, void* d_ws, size_t ws_size,
                              hipStream_t stream) {
    // setup_inputs order: x, qW, qb, qg, qbeta, kW, kb, kg, kbeta, pW, pb, pg, pbeta
    const float* x     = (const float*)d_in[0];
    const float* pW    = (const float*)d_in[9];
    const float* pb    = (const float*)d_in[10];
    const float* pg    = (const float*)d_in[11];
    const float* pbeta = (const float*)d_in[12];
    float* out = (float*)d_out;

    short* Wf = (short*)d_ws;                          // 8 KB
    float* Pf = (float*)((char*)d_ws + 8192);          // 768 B

    pack_params<<<17, 256, 0, stream>>>(pW, pb, pg, pbeta, Wf, Pf);

    dim3 grid(NWG);         // 3072 blocks
    dim3 block(256);
    fused_mfma_ln<<<grid, block, 0, stream>>>(x, Wf, Pf, out);
}

// Round 9
// 67.403 us; speedup vs baseline: 1.6614x; 1.6614x over previous
//
#include <hip/hip_runtime.h>

// channel_attention: the attention branch is the identity (softmax over m
// sums to 1 in einsum 'bdct,bdcm->bdct'). Output = LN_c(pW @ x + pb) per
// (b,d,t) column.
//
// R8 = R5 (best: 93.8us) + NON-TEMPORAL output stores. Rationale: x
// (196.6MB) has cross-replay reuse and 40% of it already hits L3
// (FETCH=115MB < 196.6MB); the out stream has NO reuse but evicts x.
// 'nt' stores keep out from polluting L3 -> x goes (near-)fully resident,
// HBM becomes a ~200MB write-dominated stream (fill kernel shows 7 TB/s).
// R7's 1KB-segment + bf16-LDS experiment regressed (write amplification
// + cvt VALU); reverted to R5's f32-LDS TILE_T=128 structure.

#define CC      64
#define TT      3000
#define TILE_T  128
#define NTB     24            // ceil(TT / TILE_T)
#define NWG     (256 * NTB)   // 6144 blocks, % 8 == 0 -> bijective swizzle
#define CPX     (NWG / 8)     // 768

typedef __attribute__((ext_vector_type(8)))  short short8;
typedef __attribute__((ext_vector_type(16))) float f32x16;
typedef __attribute__((ext_vector_type(4)))  float f32x4;

static __device__ __forceinline__ unsigned f2bf(float f) {
    // round-to-nearest-even f32 -> bf16 (inputs finite)
    unsigned u = __builtin_bit_cast(unsigned, f);
    return (u + 0x7FFFu + ((u >> 16) & 1u)) >> 16;
}

// ws layout: Wf = 4096 shorts (8 KB); Pf = 192 floats at +8192 B.
// Wf[((ct*4+kc)*64 + lane)*8 + e] = bf16(pW[co*CC + c]),
//   co = ct*32 + (lane&31), c = kc*16 + (lane>>5)*8 + e.
// Pf[a*64 + (ct*2+half)*16 + r] = {pb,pg,pbeta}[ct*32 + half*4 + (r&3) + 8*(r>>2)]
__global__ void pack_params(const float* __restrict__ pW,
                            const float* __restrict__ pb,
                            const float* __restrict__ pg,
                            const float* __restrict__ pbeta,
                            short* __restrict__ Wf, float* __restrict__ Pf)
{
    int i = blockIdx.x * 256 + threadIdx.x;
    if (i < 4096) {
        int e = i & 7, l = (i >> 3) & 63, f = i >> 9;
        int ct = f >> 2, kc = f & 3;
        int co = ct * 32 + (l & 31);
        int c  = kc * 16 + (l >> 5) * 8 + e;
        Wf[i] = (short)f2bf(pW[co * CC + c]);
    } else if (i < 4096 + 192) {
        int j = i - 4096;
        int a = j >> 6, q = j & 63;
        int r = q & 15, half = (q >> 4) & 1, ct = q >> 5;
        int co = ct * 32 + half * 4 + (r & 3) + 8 * (r >> 2);
        const float* src = (a == 0) ? pb : (a == 1) ? pg : pbeta;
        Pf[j] = src[co];
    }
}

__global__ __launch_bounds__(256, 4) void fused_mfma_ln(
    const float* __restrict__ x,    // [BD, CC, TT]
    const short* __restrict__ Wf,
    const float* __restrict__ Pf,
    float* __restrict__ out)        // [BD, CC, TT]
{
    __shared__ float xy[CC * TILE_T];   // 32 KB, [c][t] f32; reused for y

    const int bid = blockIdx.x;
    const int swz = (bid & 7) * CPX + (bid >> 3);   // XCD-chunked, bijective
    const int bd  = swz / NTB;
    const int tb  = swz - bd * NTB;
    const int t0b = tb * TILE_T;

    const int tid  = threadIdx.x;
    const int lane = tid & 63;
    const int wid  = tid >> 6;
    const int col  = lane & 31;
    const int half = lane >> 5;

    const size_t xbase = (size_t)bd * (CC * TT);

    // W fragments: 8 x 16B loads, issued first to overlap with staging.
    short8 aW[2][4];
#pragma unroll
    for (int ct = 0; ct < 2; ++ct)
#pragma unroll
        for (int kc = 0; kc < 4; ++kc)
            aW[ct][kc] = ((const short8*)Wf)[(ct * 4 + kc) * 64 + lane];

    // ---- Phase 1: stage x[64][128] f32 -> LDS via float4 (512B/row segs).
    // round r: lanes 0-31 cover row c (full 128-t span), lanes 32-63 row c+1.
    int tq = t0b + col * 4;
    if (tq > TT - 4) tq = TT - 4;       // tail clamp (dup data, never stored)
    float4 tmp[8];
#pragma unroll
    for (int r = 0; r < 8; ++r) {
        const int c = r * 8 + wid * 2 + half;
        tmp[r] = *(const float4*)(x + xbase + (size_t)c * TT + tq);
    }
#pragma unroll
    for (int r = 0; r < 8; ++r) {
        const int c = r * 8 + wid * 2 + half;
        *(float4*)&xy[c * TILE_T + col * 4] = tmp[r];   // b128, conflict-free
    }
    __syncthreads();

    // ---- Phase 2: B-frags from LDS (b32 reads, lanes stride 4B: free),
    // pack to bf16. Same (kc, half, e)->c rule as aW -> permutation cancels.
    const int tcol = wid * 32 + col;    // this wave's 32 columns
    short8 bx[4];
#pragma unroll
    for (int kc = 0; kc < 4; ++kc) {
        union { unsigned u[4]; short8 s; } cvt;
#pragma unroll
        for (int p = 0; p < 4; ++p) {
            const float a = xy[(kc * 16 + half * 8 + 2 * p)     * TILE_T + tcol];
            const float b = xy[(kc * 16 + half * 8 + 2 * p + 1) * TILE_T + tcol];
            cvt.u[p] = f2bf(a) | (f2bf(b) << 16);
        }
        bx[kc] = cvt.s;
    }

    f32x16 acc[2];
#pragma unroll
    for (int r = 0; r < 16; ++r) { acc[0][r] = 0.0f; acc[1][r] = 0.0f; }
#pragma unroll
    for (int kc = 0; kc < 4; ++kc) {
        acc[0] = __builtin_amdgcn_mfma_f32_32x32x16_bf16(aW[0][kc], bx[kc], acc[0], 0, 0, 0);
        acc[1] = __builtin_amdgcn_mfma_f32_32x32x16_bf16(aW[1][kc], bx[kc], acc[1], 0, 0, 0);
    }

    // ---- Phase 3: bias + LN stats (C/D layout: col=lane&31,
    // row = ct*32 + half*4 + (r&3) + 8*(r>>2)); shfl_xor(32) joins halves.
    float s = 0.0f, s2 = 0.0f;
#pragma unroll
    for (int ct = 0; ct < 2; ++ct) {
        const float4* pbv = (const float4*)(Pf + (ct * 2 + half) * 16);
#pragma unroll
        for (int q = 0; q < 4; ++q) {
            const float4 b4 = pbv[q];
            acc[ct][q * 4 + 0] += b4.x;
            acc[ct][q * 4 + 1] += b4.y;
            acc[ct][q * 4 + 2] += b4.z;
            acc[ct][q * 4 + 3] += b4.w;
        }
#pragma unroll
        for (int r = 0; r < 16; ++r) {
            const float v = acc[ct][r];
            s += v;
            s2 = fmaf(v, v, s2);
        }
    }
    s  += __shfl_xor(s, 32);
    s2 += __shfl_xor(s2, 32);
    const float mu   = s * (1.0f / CC);
    const float rstd = rsqrtf(s2 * (1.0f / CC) - mu * mu + 1e-5f);

    // ---- Phase 4: write final outputs back into the SAME LDS buffer.
    // Wave w touches only its own 32 columns -> safe aliasing, one barrier.
#pragma unroll
    for (int ct = 0; ct < 2; ++ct) {
        const float4* pgv = (const float4*)(Pf + 64  + (ct * 2 + half) * 16);
        const float4* pev = (const float4*)(Pf + 128 + (ct * 2 + half) * 16);
#pragma unroll
        for (int q = 0; q < 4; ++q) {
            const float4 g4 = pgv[q];
            const float4 e4 = pev[q];
            const float gg[4] = {g4.x, g4.y, g4.z, g4.w};
            const float ee[4] = {e4.x, e4.y, e4.z, e4.w};
#pragma unroll
            for (int j = 0; j < 4; ++j) {
                const int r  = q * 4 + j;
                const int co = ct * 32 + half * 4 + (r & 3) + 8 * (r >> 2);
                xy[co * TILE_T + tcol] = (acc[ct][r] - mu) * rstd * gg[j] + ee[j];
            }
        }
    }
    __syncthreads();

    // ---- Phase 5: vectorized NON-TEMPORAL stores (evict-first: out has no
    // reuse; keep L3 for x). Mirror of phase 1 (512B/row segments).
    const bool stok = (t0b + col * 4) < TT;   // quad-aligned (TT % 4 == 0)
#pragma unroll
    for (int r = 0; r < 8; ++r) {
        const int c = r * 8 + wid * 2 + half;
        const f32x4 v = *(const f32x4*)&xy[c * TILE_T + col * 4];
        if (stok)
            __builtin_nontemporal_store(
                v, (f32x4*)(out + xbase + (size_t)c * TT + t0b + col * 4));
    }
}

extern "C" void kernel_launch(void* const* d_in, const int* in_sizes, int n_in,
                              void* d_out, int out_size, void* d_ws, size_t ws_size,
                              hipStream_t stream) {
    // setup_inputs order: x, qW, qb, qg, qbeta, kW, kb, kg, kbeta, pW, pb, pg, pbeta
    const float* x     = (const float*)d_in[0];
    const float* pW    = (const float*)d_in[9];
    const float* pb    = (const float*)d_in[10];
    const float* pg    = (const float*)d_in[11];
    const float* pbeta = (const float*)d_in[12];
    float* out = (float*)d_out;

    short* Wf = (short*)d_ws;                          // 8 KB
    float* Pf = (float*)((char*)d_ws + 8192);          // 768 B

    pack_params<<<17, 256, 0, stream>>>(pW, pb, pg, pbeta, Wf, Pf);

    dim3 grid(NWG);         // 6144 blocks
    dim3 block(256);
    fused_mfma_ln<<<grid, block, 0, stream>>>(x, Wf, Pf, out);
}